// Round 9
// baseline (614.466 us; speedup 1.0000x reference)
//
#include <hip/hip_runtime.h>

// VectorQuantizer: x[16384][64] fp32, codebook[8192][64] fp32
// out = concat(discrete one-hot [16384][8192] fp32, quantized [16384][64] fp32)
// argmin_k ||x-c_k||^2 == argmax_k (x.c_k - 0.5||c_k||^2)
//
// Fully DECOUPLED pipeline (r8 post-mortem: all same-dispatch overlap schemes
// lose to clean separation):
//   k_prep  : pack codebook to B-fragment layout + 0.5||c||^2 (2 MB, L2-resident)
//   k_fill  : plain-store zero fill of discrete (the harness fill's own pattern,
//             proven 6.2-6.4 TB/s on this buffer) — runs alone, no L2 contention
//   k_comp  : pure MFMA compute, no discrete stores at all -> bestidx
//   k_finish: one-hot 1.0 + quantized gather
// Exact fp32 dots via fp16 hi/lo split, 8 MFMA terms per (rowgroup, tile).

#define NROWS 16384
#define KCODES 8192
#define DDIM 64
#define RPB 32                    // rows per compute block
#define NCOMP (NROWS / RPB)       // 512 compute blocks
#define CWAVES 8                  // compute waves per block (512 threads)
#define WCODES (KCODES / CWAVES)  // 1024 codes per wave
#define WTILES (WCODES / 16)      // 64 tiles per wave

typedef float    f32x4 __attribute__((ext_vector_type(4)));
typedef _Float16 f16x8 __attribute__((ext_vector_type(8)));

// ---------------- kernel 0: fused pack + cn2 ----------------
__global__ __launch_bounds__(256) void k_prep(const float* __restrict__ cb,
                                              f16x8* __restrict__ packed,
                                              float* __restrict__ cn2) {
    int tid = blockIdx.x * 256 + threadIdx.x;   // 0..32767
    int Tg = tid >> 6, L = tid & 63;
    int lane15 = L & 15, quad = L >> 4;
    int code = Tg * 16 + lane15;
    const float* p = cb + (size_t)code * DDIM + quad * 8;
    f16x8 h0, l0, h1, l1;
    float s = 0.f;
#pragma unroll
    for (int j = 0; j < 8; ++j) {
        float v = p[j];
        _Float16 h = (_Float16)v;
        h0[j] = h; l0[j] = (_Float16)(v - (float)h);
        s = fmaf(v, v, s);
        float w = p[32 + j];
        _Float16 h2 = (_Float16)w;
        h1[j] = h2; l1[j] = (_Float16)(w - (float)h2);
        s = fmaf(w, w, s);
    }
    s += __shfl_xor(s, 16, 64);
    s += __shfl_xor(s, 32, 64);
    if (quad == 0) cn2[code] = 0.5f * s;
    f16x8* out = packed + (size_t)Tg * 256 + L;
    out[0]   = h0;
    out[64]  = h1;
    out[128] = l0;
    out[192] = l1;
}

// ---------------- kernel 1: dedicated zero fill (plain stores, fill-kernel style) ----
__global__ __launch_bounds__(256) void k_fill(float* __restrict__ discrete) {
    f32x4* dst = (f32x4*)discrete + (size_t)blockIdx.x * 16384;   // 256 KiB/block
    const f32x4 zero4 = {0.f, 0.f, 0.f, 0.f};
#pragma unroll 8
    for (int i = 0; i < 64; ++i)
        dst[i * 256 + threadIdx.x] = zero4;
}

// ---------------- kernel 2: pure compute (MFMA + argmax), no big stores ----------------
__global__ __launch_bounds__(512, 4) void k_comp(const float* __restrict__ x,
                                                 const f16x8* __restrict__ packed,
                                                 const float* __restrict__ cn2,
                                                 int* __restrict__ bestidx) {
    const int t = threadIdx.x;
    const int L = t & 63;
    const int w = t >> 6;                 // wave = code eighth
    const int row0 = blockIdx.x * RPB;
    const int lane15 = L & 15;
    const int quad = L >> 4;

    // A fragments: two row groups, exact hi/lo split
    const float* xa = x + (size_t)(row0 + lane15) * DDIM + quad * 8;
    const float* xb = xa + 16 * DDIM;
    f16x8 Ah0, Al0, Ah1, Al1, Bh0, Bl0, Bh1, Bl1;
#pragma unroll
    for (int j = 0; j < 8; ++j) {
        float v = xa[j];        _Float16 h = (_Float16)v;
        Ah0[j] = h; Al0[j] = (_Float16)(v - (float)h);
        v = xa[32 + j];         h = (_Float16)v;
        Ah1[j] = h; Al1[j] = (_Float16)(v - (float)h);
        v = xb[j];              h = (_Float16)v;
        Bh0[j] = h; Bl0[j] = (_Float16)(v - (float)h);
        v = xb[32 + j];         h = (_Float16)v;
        Bh1[j] = h; Bl1[j] = (_Float16)(v - (float)h);
    }

    float bvA[4], bvB[4];
    int   biA[4], biB[4];
#pragma unroll
    for (int r = 0; r < 4; ++r) { bvA[r] = bvB[r] = -3.4e38f; biA[r] = biB[r] = 0; }

    const int code0 = w * WCODES;
    const f16x8* pb = packed + (size_t)(code0 >> 4) * 256 + L;

    for (int i = 0; i < WTILES; ++i) {
        f16x8 ch0 = pb[0], ch1 = pb[64], cl0 = pb[128], cl1 = pb[192];
        const int ct = code0 + i * 16;
        float cn = cn2[ct + lane15];
        f32x4 accA = {-cn, -cn, -cn, -cn};
        f32x4 accB = accA;
        accA = __builtin_amdgcn_mfma_f32_16x16x32_f16(Ah0, ch0, accA, 0, 0, 0);
        accB = __builtin_amdgcn_mfma_f32_16x16x32_f16(Bh0, ch0, accB, 0, 0, 0);
        accA = __builtin_amdgcn_mfma_f32_16x16x32_f16(Ah1, ch1, accA, 0, 0, 0);
        accB = __builtin_amdgcn_mfma_f32_16x16x32_f16(Bh1, ch1, accB, 0, 0, 0);
        accA = __builtin_amdgcn_mfma_f32_16x16x32_f16(Al0, ch0, accA, 0, 0, 0);
        accB = __builtin_amdgcn_mfma_f32_16x16x32_f16(Bl0, ch0, accB, 0, 0, 0);
        accA = __builtin_amdgcn_mfma_f32_16x16x32_f16(Al1, ch1, accA, 0, 0, 0);
        accB = __builtin_amdgcn_mfma_f32_16x16x32_f16(Bl1, ch1, accB, 0, 0, 0);
        accA = __builtin_amdgcn_mfma_f32_16x16x32_f16(Ah0, cl0, accA, 0, 0, 0);
        accB = __builtin_amdgcn_mfma_f32_16x16x32_f16(Bh0, cl0, accB, 0, 0, 0);
        accA = __builtin_amdgcn_mfma_f32_16x16x32_f16(Ah1, cl1, accA, 0, 0, 0);
        accB = __builtin_amdgcn_mfma_f32_16x16x32_f16(Bh1, cl1, accB, 0, 0, 0);
        accA = __builtin_amdgcn_mfma_f32_16x16x32_f16(Al0, cl0, accA, 0, 0, 0);
        accB = __builtin_amdgcn_mfma_f32_16x16x32_f16(Bl0, cl0, accB, 0, 0, 0);
        accA = __builtin_amdgcn_mfma_f32_16x16x32_f16(Al1, cl1, accA, 0, 0, 0);
        accB = __builtin_amdgcn_mfma_f32_16x16x32_f16(Bl1, cl1, accB, 0, 0, 0);

        const int vcode = ct + lane15;
#pragma unroll
        for (int r = 0; r < 4; ++r) {
            if (accA[r] > bvA[r]) { bvA[r] = accA[r]; biA[r] = vcode; }
            if (accB[r] > bvB[r]) { bvB[r] = accB[r]; biB[r] = vcode; }
        }
        pb += 256;
    }

    // 16-lane butterfly per quad, then cross-wave LDS reduce
    __shared__ float rv[RPB][CWAVES + 1];
    __shared__ int   ri[RPB][CWAVES + 1];
#pragma unroll
    for (int r = 0; r < 4; ++r) {
        float vA = bvA[r], vB = bvB[r];
        int  iA = biA[r], iB = biB[r];
#pragma unroll
        for (int m = 1; m < 16; m <<= 1) {
            float oA = __shfl_xor(vA, m, 64); int xA = __shfl_xor(iA, m, 64);
            if (oA > vA || (oA == vA && xA < iA)) { vA = oA; iA = xA; }
            float oB = __shfl_xor(vB, m, 64); int xB = __shfl_xor(iB, m, 64);
            if (oB > vB || (oB == vB && xB < iB)) { vB = oB; iB = xB; }
        }
        if (lane15 == 0) {
            rv[quad * 4 + r][w] = vA;      ri[quad * 4 + r][w] = iA;
            rv[16 + quad * 4 + r][w] = vB; ri[16 + quad * 4 + r][w] = iB;
        }
    }
    __syncthreads();
    if (t < RPB) {
        float bv = rv[t][0];
        int   bi = ri[t][0];
#pragma unroll
        for (int w2 = 1; w2 < CWAVES; ++w2) {  // ascending wave = ascending codes
            float v = rv[t][w2];
            int  id = ri[t][w2];
            if (v > bv || (v == bv && id < bi)) { bv = v; bi = id; }
        }
        bestidx[row0 + t] = bi;
    }
}

// ---------------- kernel 3: one-hot 1.0 + quantized gather ----------------
__global__ __launch_bounds__(256) void k_finish(const float* __restrict__ cb,
                                                const int* __restrict__ bestidx,
                                                float* __restrict__ discrete,
                                                float* __restrict__ quantized) {
    __shared__ int sidx[256];
    const int t = threadIdx.x;
    const int row0 = blockIdx.x * 256;
    const int row = row0 + t;
    int bi = bestidx[row];
    sidx[t] = bi;
    discrete[(size_t)row * KCODES + bi] = 1.0f;   // after fill (stream order)
    __syncthreads();
#pragma unroll
    for (int i = 0; i < 16; ++i) {
        int e = i * 256 + t;
        int r = e >> 4, c = e & 15;
        float4 v = *((const float4*)(cb + (size_t)sidx[r] * DDIM) + c);
        *((float4*)(quantized + (size_t)(row0 + r) * DDIM) + c) = v;
    }
}

extern "C" void kernel_launch(void* const* d_in, const int* in_sizes, int n_in,
                              void* d_out, int out_size, void* d_ws, size_t ws_size,
                              hipStream_t stream) {
    const float* x  = (const float*)d_in[0];   // 16*32*32*64
    const float* cb = (const float*)d_in[1];   // 8192*64

    float* discrete  = (float*)d_out;                          // 16384*8192
    float* quantized = (float*)d_out + (size_t)NROWS * KCODES; // 16384*64

    // packed B-fragments (2 MB) live in the quantized output region (4 MB):
    // k_comp only reads it; k_finish overwrites quantized afterwards.
    f16x8* packed = (f16x8*)quantized;

    float* cn2     = (float*)d_ws;             // 8192 floats
    int*   bestidx = (int*)(cn2 + KCODES);     // 16384 ints

    k_prep<<<(KCODES / 16) * 64 / 256, 256, 0, stream>>>(cb, packed, cn2);
    k_fill<<<(size_t)NROWS * KCODES / 4 / 16384, 256, 0, stream>>>(discrete);  // 2048 blocks
    k_comp<<<NCOMP, 512, 0, stream>>>(x, packed, cn2, bestidx);
    k_finish<<<NROWS / 256, 256, 0, stream>>>(cb, bestidx, discrete, quantized);
}

// Round 10
// 538.195 us; speedup vs baseline: 1.1417x; 1.1417x over previous
//
#include <hip/hip_runtime.h>

// VectorQuantizer: x[16384][64] fp32, codebook[8192][64] fp32
// out = concat(discrete one-hot [16384][8192] fp32, quantized [16384][64] fp32)
// argmin_k ||x-c_k||^2 == argmax_k (x.c_k - 0.5||c_k||^2)
//
// r9 post-mortem: pure compute (~150us) dominates; stores hide under it when
// NT-interleaved (r6). This round: r6 structure with 256-thread blocks
// (4 waves x 2048 codes, 4 independent blocks/CU to desync load phases) +
// restored 1-tile register prefetch of B-frags + cn2.
// Exact fp32 dots via fp16 hi/lo split, 8 MFMA terms per (rowgroup, tile);
// per-(row,code) term order bit-identical to rounds 4-9.

#define NROWS 16384
#define KCODES 8192
#define DDIM 64
#define RPB 32                    // rows per block
#define CWAVES 4                  // waves per block (256 threads)
#define WCODES (KCODES / CWAVES)  // 2048 codes per wave
#define WTILES (WCODES / 16)      // 128 tiles per wave

typedef float    f32x4 __attribute__((ext_vector_type(4)));
typedef _Float16 f16x8 __attribute__((ext_vector_type(8)));

// ---------------- kernel 0: fused pack + cn2 ----------------
// thread (Tg, L): code = Tg*16 + (L&15), k-slice = (L>>4)*8 (+32).
// packed[Tg][frag][lane]: frag 0=hi k0..31, 1=hi k32..63, 2=lo k0..31, 3=lo k32..63.
__global__ __launch_bounds__(256) void k_prep(const float* __restrict__ cb,
                                              f16x8* __restrict__ packed,
                                              float* __restrict__ cn2) {
    int tid = blockIdx.x * 256 + threadIdx.x;   // 0..32767
    int Tg = tid >> 6, L = tid & 63;
    int lane15 = L & 15, quad = L >> 4;
    int code = Tg * 16 + lane15;
    const float* p = cb + (size_t)code * DDIM + quad * 8;
    f16x8 h0, l0, h1, l1;
    float s = 0.f;
#pragma unroll
    for (int j = 0; j < 8; ++j) {
        float v = p[j];
        _Float16 h = (_Float16)v;
        h0[j] = h; l0[j] = (_Float16)(v - (float)h);
        s = fmaf(v, v, s);
        float w = p[32 + j];
        _Float16 h2 = (_Float16)w;
        h1[j] = h2; l1[j] = (_Float16)(w - (float)h2);
        s = fmaf(w, w, s);
    }
    s += __shfl_xor(s, 16, 64);
    s += __shfl_xor(s, 32, 64);
    if (quad == 0) cn2[code] = 0.5f * s;
    f16x8* out = packed + (size_t)Tg * 256 + L;
    out[0]   = h0;
    out[64]  = h1;
    out[128] = l0;
    out[192] = l1;
}

// ---------------- kernel 1: main MFMA + argmax + NT zero-fill + one-hot ----------------
__global__ __launch_bounds__(256, 4) void k_main(const float* __restrict__ x,
                                                 const f16x8* __restrict__ packed,
                                                 const float* __restrict__ cn2,
                                                 float* __restrict__ discrete,
                                                 int* __restrict__ bestidx) {
    const int t = threadIdx.x;
    const int L = t & 63;
    const int w = t >> 6;                 // wave = code quarter (ascending codes)
    const int row0 = blockIdx.x * RPB;
    const int lane15 = L & 15;
    const int quad = L >> 4;

    // ---- A fragments: two row groups, exact hi/lo split ----
    const float* xa = x + (size_t)(row0 + lane15) * DDIM + quad * 8;
    const float* xb = xa + 16 * DDIM;
    f16x8 Ah0, Al0, Ah1, Al1, Bh0, Bl0, Bh1, Bl1;
#pragma unroll
    for (int j = 0; j < 8; ++j) {
        float v = xa[j];        _Float16 h = (_Float16)v;
        Ah0[j] = h; Al0[j] = (_Float16)(v - (float)h);
        v = xa[32 + j];         h = (_Float16)v;
        Ah1[j] = h; Al1[j] = (_Float16)(v - (float)h);
        v = xb[j];              h = (_Float16)v;
        Bh0[j] = h; Bl0[j] = (_Float16)(v - (float)h);
        v = xb[32 + j];         h = (_Float16)v;
        Bh1[j] = h; Bl1[j] = (_Float16)(v - (float)h);
    }

    float bvA[4], bvB[4];
    int   biA[4], biB[4];
#pragma unroll
    for (int r = 0; r < 4; ++r) { bvA[r] = bvB[r] = -3.4e38f; biA[r] = biB[r] = 0; }

    const f32x4 zero4 = {0.f, 0.f, 0.f, 0.f};
    const int code0 = w * WCODES;
    const f16x8* pb = packed + (size_t)(code0 >> 4) * 256 + L;

    // preload tile 0 (B frags + cn)
    f16x8 ch0 = pb[0], ch1 = pb[64], cl0 = pb[128], cl1 = pb[192];
    float cn = cn2[code0 + lane15];
    f32x4* zdst = (f32x4*)(discrete + (size_t)row0 * KCODES);   // 65536 f32x4/block

    for (int i = 0; i < WTILES; ++i) {
        // ---- prefetch tile i+1 first (stays in flight under the MFMA burst) ----
        const int inext = (i + 1 < WTILES) ? i + 1 : i;
        const f16x8* pn = packed + (size_t)((code0 >> 4) + inext) * 256 + L;
        f16x8 n0 = pn[0], n1 = pn[64], n2 = pn[128], n3 = pn[192];
        float cnn = cn2[code0 + inext * 16 + lane15];

        // ---- NT zero-fill: 2 f32x4 per thread per tile (65536 total/block) ----
        {
            int g = i * 512 + t;
            __builtin_nontemporal_store(zero4, zdst + g);
            __builtin_nontemporal_store(zero4, zdst + g + 256);
        }

        // ---- compute current tile ----
        const int ct = code0 + i * 16;
        f32x4 accA = {-cn, -cn, -cn, -cn};
        f32x4 accB = accA;
        accA = __builtin_amdgcn_mfma_f32_16x16x32_f16(Ah0, ch0, accA, 0, 0, 0);
        accB = __builtin_amdgcn_mfma_f32_16x16x32_f16(Bh0, ch0, accB, 0, 0, 0);
        accA = __builtin_amdgcn_mfma_f32_16x16x32_f16(Ah1, ch1, accA, 0, 0, 0);
        accB = __builtin_amdgcn_mfma_f32_16x16x32_f16(Bh1, ch1, accB, 0, 0, 0);
        accA = __builtin_amdgcn_mfma_f32_16x16x32_f16(Al0, ch0, accA, 0, 0, 0);
        accB = __builtin_amdgcn_mfma_f32_16x16x32_f16(Bl0, ch0, accB, 0, 0, 0);
        accA = __builtin_amdgcn_mfma_f32_16x16x32_f16(Al1, ch1, accA, 0, 0, 0);
        accB = __builtin_amdgcn_mfma_f32_16x16x32_f16(Bl1, ch1, accB, 0, 0, 0);
        accA = __builtin_amdgcn_mfma_f32_16x16x32_f16(Ah0, cl0, accA, 0, 0, 0);
        accB = __builtin_amdgcn_mfma_f32_16x16x32_f16(Bh0, cl0, accB, 0, 0, 0);
        accA = __builtin_amdgcn_mfma_f32_16x16x32_f16(Ah1, cl1, accA, 0, 0, 0);
        accB = __builtin_amdgcn_mfma_f32_16x16x32_f16(Bh1, cl1, accB, 0, 0, 0);
        accA = __builtin_amdgcn_mfma_f32_16x16x32_f16(Al0, cl0, accA, 0, 0, 0);
        accB = __builtin_amdgcn_mfma_f32_16x16x32_f16(Bl0, cl0, accB, 0, 0, 0);
        accA = __builtin_amdgcn_mfma_f32_16x16x32_f16(Al1, cl1, accA, 0, 0, 0);
        accB = __builtin_amdgcn_mfma_f32_16x16x32_f16(Bl1, cl1, accB, 0, 0, 0);

        const int vcode = ct + lane15;
#pragma unroll
        for (int r = 0; r < 4; ++r) {
            if (accA[r] > bvA[r]) { bvA[r] = accA[r]; biA[r] = vcode; }
            if (accB[r] > bvB[r]) { bvB[r] = accB[r]; biB[r] = vcode; }
        }
        ch0 = n0; ch1 = n1; cl0 = n2; cl1 = n3; cn = cnn;
    }

    // ---- 16-lane butterfly per quad, then cross-wave LDS reduce ----
    __shared__ float rv[RPB][CWAVES + 1];
    __shared__ int   ri[RPB][CWAVES + 1];
#pragma unroll
    for (int r = 0; r < 4; ++r) {
        float vA = bvA[r], vB = bvB[r];
        int  iA = biA[r], iB = biB[r];
#pragma unroll
        for (int m = 1; m < 16; m <<= 1) {
            float oA = __shfl_xor(vA, m, 64); int xA = __shfl_xor(iA, m, 64);
            if (oA > vA || (oA == vA && xA < iA)) { vA = oA; iA = xA; }
            float oB = __shfl_xor(vB, m, 64); int xB = __shfl_xor(iB, m, 64);
            if (oB > vB || (oB == vB && xB < iB)) { vB = oB; iB = xB; }
        }
        if (lane15 == 0) {
            rv[quad * 4 + r][w] = vA;      ri[quad * 4 + r][w] = iA;
            rv[16 + quad * 4 + r][w] = vB; ri[16 + quad * 4 + r][w] = iB;
        }
    }
    __syncthreads();   // drains NT zero stores before the 1.0 write
    if (t < RPB) {
        float bv = rv[t][0];
        int   bi = ri[t][0];
#pragma unroll
        for (int w2 = 1; w2 < CWAVES; ++w2) {  // ascending wave = ascending codes
            float v = rv[t][w2];
            int  id = ri[t][w2];
            if (v > bv || (v == bv && id < bi)) { bv = v; bi = id; }
        }
        int row = row0 + t;
        bestidx[row] = bi;
        discrete[(size_t)row * KCODES + bi] = 1.0f;
    }
}

// ---------------- kernel 2: quantized gather ----------------
__global__ __launch_bounds__(256) void k_finish(const float* __restrict__ cb,
                                                const int* __restrict__ bestidx,
                                                float* __restrict__ quantized) {
    __shared__ int sidx[256];
    const int t = threadIdx.x;
    const int row0 = blockIdx.x * 256;
    sidx[t] = bestidx[row0 + t];
    __syncthreads();
#pragma unroll
    for (int i = 0; i < 16; ++i) {
        int e = i * 256 + t;
        int r = e >> 4, c = e & 15;
        float4 v = *((const float4*)(cb + (size_t)sidx[r] * DDIM) + c);
        *((float4*)(quantized + (size_t)(row0 + r) * DDIM) + c) = v;
    }
}

extern "C" void kernel_launch(void* const* d_in, const int* in_sizes, int n_in,
                              void* d_out, int out_size, void* d_ws, size_t ws_size,
                              hipStream_t stream) {
    const float* x  = (const float*)d_in[0];   // 16*32*32*64
    const float* cb = (const float*)d_in[1];   // 8192*64

    float* discrete  = (float*)d_out;                          // 16384*8192
    float* quantized = (float*)d_out + (size_t)NROWS * KCODES; // 16384*64

    // packed B-fragments (2 MB) live in the quantized output region (4 MB):
    // k_main only reads it; k_finish overwrites quantized afterwards.
    f16x8* packed = (f16x8*)quantized;

    float* cn2     = (float*)d_ws;             // 8192 floats
    int*   bestidx = (int*)(cn2 + KCODES);     // 16384 ints

    k_prep<<<(KCODES / 16) * 64 / 256, 256, 0, stream>>>(cb, packed, cn2);
    k_main<<<NROWS / RPB, CWAVES * 64, 0, stream>>>(x, packed, cn2, discrete, bestidx);
    k_finish<<<NROWS / 256, 256, 0, stream>>>(cb, bestidx, quantized);
}